// Round 14
// baseline (946.229 us; speedup 1.0000x reference)
//
#include <hip/hip_runtime.h>
#include <math.h>

#define BB 32
#define TT 128
#define EE 128
#define HD 128
#define G4 512   // 4*H
#define NV 32000

typedef _Float16 f16x2  __attribute__((ext_vector_type(2)));
typedef _Float16 f16x4v __attribute__((ext_vector_type(4)));
typedef _Float16 f16x8  __attribute__((ext_vector_type(8)));
typedef float    f32x4  __attribute__((ext_vector_type(4)));

// ---------------- Kernel A (fused): blocks 0..1999 split Wd, 2000..2511 embed ----------------
__global__ __launch_bounds__(256) void k_prep(
    const int* __restrict__ inputs, const float* __restrict__ emb,
    const float* __restrict__ W0, const float* __restrict__ b0,
    float* __restrict__ Z0x,
    const float* __restrict__ Wd, _Float16* __restrict__ Whi, _Float16* __restrict__ Wlo)
{
    if (blockIdx.x < 2000) {
        if (Whi == nullptr) return;   // small-ws fallback: no split buffers
        const int g = blockIdx.x * 256 + threadIdx.x;
        const int chunk = g >> 6;           // 0..7999
        const int lane = g & 63;
        const int ntile = chunk >> 2;
        const int kstep = chunk & 3;
        const int n = ntile * 16 + (lane & 15);
        const int kb = kstep * 32 + (lane >> 4) * 8;
        _Float16 hi[8], lo[8];
        #pragma unroll
        for (int j = 0; j < 8; ++j) {
            float v = Wd[(size_t)(kb + j) * NV + n];
            hi[j] = (_Float16)v;
            lo[j] = (_Float16)(v - (float)hi[j]);
        }
        *(float4*)&Whi[(size_t)chunk * 512 + lane * 8] = *(const float4*)hi;
        *(float4*)&Wlo[(size_t)chunk * 512 + lane * 8] = *(const float4*)lo;
        return;
    }
    __shared__ float xs[8][EE];
    const int r0 = (blockIdx.x - 2000) * 8;
    const int tid = threadIdx.x;
    for (int i = tid; i < 8 * EE; i += 256) {
        int r = i >> 7, e = i & 127;
        int tok = inputs[r0 + r];
        xs[r][e] = emb[tok * EE + e];
    }
    __syncthreads();
    const int c2 = tid * 2;
    float2 bb2 = *(const float2*)&b0[c2];
    float acc[8][2];
    #pragma unroll
    for (int r = 0; r < 8; ++r) { acc[r][0] = bb2.x; acc[r][1] = bb2.y; }
    for (int e = 0; e < EE; ++e) {
        float2 w = *(const float2*)&W0[e * G4 + c2];
        #pragma unroll
        for (int r = 0; r < 8; ++r) {
            float x = xs[r][e];
            acc[r][0] = fmaf(x, w.x, acc[r][0]);
            acc[r][1] = fmaf(x, w.y, acc[r][1]);
        }
    }
    #pragma unroll
    for (int r = 0; r < 8; ++r) {
        float2 o2; o2.x = acc[r][0]; o2.y = acc[r][1];
        *(float2*)&Z0x[(size_t)(r0 + r) * G4 + c2] = o2;
    }
}

// ---------------- Kernel B: 2-layer LSTM via MFMA, IN-REGISTER gates ----------------
// 4 blocks x 256 thr. Wave w owns units [w*32, w*32+32) of ALL FOUR gates:
// acc n = 2*gate + half covers columns gate*128 + w*32 + half*16 + (lane&15).
// MFMA D-layout (row=batch, col=unit) then gives each lane all 4 gate-z for
// its (batch,unit) IN REGISTERS -> no zbuf LDS round-trip, 2 barriers/step.
// Z0x is the C-initializer of the U0 MFMAs (x has exactly D-layout); b1 the
// C-init of the W1 MFMAs. U1*h1 computed in phase A, acc held in-lane to
// phase C. U0 frags in VGPR; W1,U1 frags pinned to AGPR (round-13-verified).
__device__ __forceinline__ float sigf(float x) {
    return __builtin_amdgcn_rcpf(1.f + __builtin_amdgcn_exp2f(x * -1.44269504088896f));
}
__device__ __forceinline__ float tanh_f(float x) {
    return 1.f - 2.f * __builtin_amdgcn_rcpf(1.f + __builtin_amdgcn_exp2f(x * 2.88539008177793f));
}
__device__ __forceinline__ f16x8 ldfrag(const float* __restrict__ M, int col, int k0) {
    f16x8 v;
    #pragma unroll
    for (int j = 0; j < 8; ++j) v[j] = (_Float16)M[(size_t)(k0 + j) * G4 + col];
    return v;
}

#define REP8(X) X(0) X(1) X(2) X(3) X(4) X(5) X(6) X(7)
#define MFMA(acc, a, b) acc = __builtin_amdgcn_mfma_f32_16x16x32_f16(a, b, acc, 0, 0, 0)
#define TSTR (TT * G4)

#define DECLF(n) f16x8 u0_##n##_0, u0_##n##_1, u0_##n##_2, u0_##n##_3, \
                       w1_##n##_0, w1_##n##_1, w1_##n##_2, w1_##n##_3, \
                       u1_##n##_0, u1_##n##_1, u1_##n##_2, u1_##n##_3; \
                 f32x4 aU1_##n, aZ_##n; float b1c_##n; int col_##n;

// gate-permuted column: n = 2*gate + half
#define LOADF(n) { col_##n = ((n) >> 1) * 128 + wu + ((n) & 1) * 16 + lo16; \
    const int cn = col_##n; \
    u0_##n##_0 = ldfrag(U0, cn, khi);      u0_##n##_1 = ldfrag(U0, cn, 32 + khi); \
    u0_##n##_2 = ldfrag(U0, cn, 64 + khi); u0_##n##_3 = ldfrag(U0, cn, 96 + khi); \
    w1_##n##_0 = ldfrag(W1, cn, khi);      w1_##n##_1 = ldfrag(W1, cn, 32 + khi); \
    w1_##n##_2 = ldfrag(W1, cn, 64 + khi); w1_##n##_3 = ldfrag(W1, cn, 96 + khi); \
    asm("" : "+a"(w1_##n##_0), "+a"(w1_##n##_1), "+a"(w1_##n##_2), "+a"(w1_##n##_3)); \
    u1_##n##_0 = ldfrag(U1, cn, khi);      u1_##n##_1 = ldfrag(U1, cn, 32 + khi); \
    u1_##n##_2 = ldfrag(U1, cn, 64 + khi); u1_##n##_3 = ldfrag(U1, cn, 96 + khi); \
    asm("" : "+a"(u1_##n##_0), "+a"(u1_##n##_1), "+a"(u1_##n##_2), "+a"(u1_##n##_3)); \
    b1c_##n = b1[cn]; }

#define PU1(n) { f32x4 a = {0.f, 0.f, 0.f, 0.f}; \
    MFMA(a, hb0, u1_##n##_0); MFMA(a, hb1, u1_##n##_1); \
    MFMA(a, hb2, u1_##n##_2); MFMA(a, hb3, u1_##n##_3); aU1_##n = a; }

#define PU0(n) { const float* zc = zxt + col_##n; f32x4 a; \
    a[0] = zc[0]; a[1] = zc[TSTR]; a[2] = zc[2 * TSTR]; a[3] = zc[3 * TSTR]; \
    MFMA(a, ha0, u0_##n##_0); MFMA(a, ha1, u0_##n##_1); \
    MFMA(a, ha2, u0_##n##_2); MFMA(a, ha3, u0_##n##_3); aZ_##n = a; }

#define PW1(n) { f32x4 a = {b1c_##n, b1c_##n, b1c_##n, b1c_##n}; \
    MFMA(a, ha0, w1_##n##_0); MFMA(a, ha1, w1_##n##_1); \
    MFMA(a, ha2, w1_##n##_2); MFMA(a, ha3, w1_##n##_3); \
    aZ_##n = a + aU1_##n; }

// gates: acc n=2g+h -> zi:aZ_h, zf:aZ_{2+h}, zc:aZ_{4+h}, zo:aZ_{6+h}
#define G0R(nI, nF, nC, nO, CS, h, r) { \
    float ig = sigf(aZ_##nI[r]), fg = sigf(aZ_##nF[r]), og = sigf(aZ_##nO[r]); \
    float gg = tanh_f(aZ_##nC[r]); \
    float cn = fg * CS[r] + ig * gg; CS[r] = cn; \
    h0c[bq4 + r][wu + lo16 + 16 * (h)] = (_Float16)(og * tanh_f(cn)); }

#define G1R(nI, nF, nC, nO, CS, h, r) { \
    float ig = sigf(aZ_##nI[r]), fg = sigf(aZ_##nF[r]), og = sigf(aZ_##nO[r]); \
    float gg = tanh_f(aZ_##nC[r]); \
    float cn = fg * CS[r] + ig * gg; CS[r] = cn; float hn = og * tanh_f(cn); \
    h1c[bq4 + r][wu + lo16 + 16 * (h)] = (_Float16)hn; \
    yb[(size_t)(r) * TT * HD + (size_t)t * HD + 16 * (h)] = hn; }

__global__ __launch_bounds__(256, 1) void k_lstm_m2(
    const float* __restrict__ Z0x,
    const float* __restrict__ U0, const float* __restrict__ W1,
    const float* __restrict__ U1, const float* __restrict__ b1,
    float* __restrict__ y)
{
    const int tid  = threadIdx.x;
    const int lane = tid & 63;
    const int wu   = (tid >> 6) * 32;      // wave's unit base
    const int lo16 = lane & 15;
    const int khi  = (lane >> 4) * 8;
    const int B0   = blockIdx.x * 8;       // batch base
    const int bq4  = (lane >> 4) * 4;      // batch group (valid for lane<32)
    const int xr   = ((lane >> 4) & 1) * 4;  // safe batch base for x loads (all lanes)

    __shared__ _Float16 h0p[2][16][136];   // double-buffered, rows 8-15 stay 0
    __shared__ _Float16 h1p[2][16][136];

    REP8(DECLF)
    REP8(LOADF)

    const float* zx0 = Z0x + ((size_t)(B0 + xr) * TT) * G4;
    float* yb = y + ((size_t)(B0 + bq4) * TT) * HD + wu + lo16;

    f32x4 c0a = {0.f,0.f,0.f,0.f}, c0b = {0.f,0.f,0.f,0.f};
    f32x4 c1a = {0.f,0.f,0.f,0.f}, c1b = {0.f,0.f,0.f,0.f};

    for (int i = tid; i < 2 * 16 * 136; i += 256) {
        (&h0p[0][0][0])[i] = (_Float16)0.f;
        (&h1p[0][0][0])[i] = (_Float16)0.f;
    }
    __syncthreads();

    for (int t = 0; t < TT; ++t) {
        const int p = t & 1;
        const _Float16 (*h0r)[136] = h0p[p ^ 1];
        const _Float16 (*h1r)[136] = h1p[p ^ 1];
        _Float16 (*h0c)[136] = h0p[p];
        _Float16 (*h1c)[136] = h1p[p];
        const float* zxt = zx0 + (size_t)t * G4;

        // ---- phase A: aU1 = U1^T h1_{t-1};  aZ = x_t + U0^T h0_{t-1} ----
        {
            f16x8 hb0 = *(const f16x8*)&h1r[lo16][khi];
            f16x8 hb1 = *(const f16x8*)&h1r[lo16][32 + khi];
            f16x8 hb2 = *(const f16x8*)&h1r[lo16][64 + khi];
            f16x8 hb3 = *(const f16x8*)&h1r[lo16][96 + khi];
            REP8(PU1)
            f16x8 ha0 = *(const f16x8*)&h0r[lo16][khi];
            f16x8 ha1 = *(const f16x8*)&h0r[lo16][32 + khi];
            f16x8 ha2 = *(const f16x8*)&h0r[lo16][64 + khi];
            f16x8 ha3 = *(const f16x8*)&h0r[lo16][96 + khi];
            REP8(PU0)
        }
        // ---- gates 0 (in-register) -> h0_t ----
        if (lane < 32) {
            G0R(0, 2, 4, 6, c0a, 0, 0) G0R(0, 2, 4, 6, c0a, 0, 1)
            G0R(0, 2, 4, 6, c0a, 0, 2) G0R(0, 2, 4, 6, c0a, 0, 3)
            G0R(1, 3, 5, 7, c0b, 1, 0) G0R(1, 3, 5, 7, c0b, 1, 1)
            G0R(1, 3, 5, 7, c0b, 1, 2) G0R(1, 3, 5, 7, c0b, 1, 3)
        }
        __syncthreads();   // h0_t visible to all waves

        // ---- phase C: aZ = b1 + W1^T h0_t + aU1 ----
        {
            f16x8 ha0 = *(const f16x8*)&h0c[lo16][khi];
            f16x8 ha1 = *(const f16x8*)&h0c[lo16][32 + khi];
            f16x8 ha2 = *(const f16x8*)&h0c[lo16][64 + khi];
            f16x8 ha3 = *(const f16x8*)&h0c[lo16][96 + khi];
            REP8(PW1)
        }
        // ---- gates 1 (in-register) -> h1_t, y ----
        if (lane < 32) {
            G1R(0, 2, 4, 6, c1a, 0, 0) G1R(0, 2, 4, 6, c1a, 0, 1)
            G1R(0, 2, 4, 6, c1a, 0, 2) G1R(0, 2, 4, 6, c1a, 0, 3)
            G1R(1, 3, 5, 7, c1b, 1, 0) G1R(1, 3, 5, 7, c1b, 1, 1)
            G1R(1, 3, 5, 7, c1b, 1, 2) G1R(1, 3, 5, 7, c1b, 1, 3)
        }
        __syncthreads();   // h1_t visible before next step's phase A
    }
}

// ---------------- Prep: split y into f16 hi/lo, MFMA-fragment-packed ----------------
__global__ __launch_bounds__(256) void k_ysplit(
    const float* __restrict__ y, _Float16* __restrict__ yhi, _Float16* __restrict__ ylo)
{
    const int g = blockIdx.x * 256 + threadIdx.x;
    const int chunk = g >> 6;           // 0..1023
    const int lane = g & 63;
    const int mtile = chunk >> 2;
    const int kstep = chunk & 3;
    const int row = mtile * 16 + (lane & 15);
    const int kb = kstep * 32 + (lane >> 4) * 8;
    _Float16 hi[8], lo[8];
    #pragma unroll
    for (int j = 0; j < 8; ++j) {
        float v = y[(size_t)row * HD + kb + j];
        hi[j] = (_Float16)v;
        lo[j] = (_Float16)(v - (float)hi[j]);
    }
    *(float4*)&yhi[(size_t)chunk * 512 + lane * 8] = *(const float4*)hi;
    *(float4*)&ylo[(size_t)chunk * 512 + lane * 8] = *(const float4*)lo;
}

// ---------------- Kernel C (MFMA): out = y @ Wd + bd via f16 hi/lo split ----------------
__global__ __launch_bounds__(256) void k_dense_mfma(
    const _Float16* __restrict__ yhi, const _Float16* __restrict__ ylo,
    const _Float16* __restrict__ Whi, const _Float16* __restrict__ Wlo,
    const float* __restrict__ bd, float* __restrict__ out)
{
    const int tid = threadIdx.x;
    const int w = tid >> 6;
    const int lane = tid & 63;
    const int mtile = blockIdx.x * 4 + w;
    const int nt0 = blockIdx.y * 20;

    f16x8 Ah[4], Al[4];
    #pragma unroll
    for (int k = 0; k < 4; ++k) {
        Ah[k] = *(const f16x8*)&yhi[(size_t)(mtile * 4 + k) * 512 + lane * 8];
        Al[k] = *(const f16x8*)&ylo[(size_t)(mtile * 4 + k) * 512 + lane * 8];
    }

    const int m0 = mtile * 16;
    const int r0 = (lane >> 4) * 4;          // C/D row group (m89 mapping)

    for (int nt = 0; nt < 20; ++nt) {
        const int ntile = nt0 + nt;
        const size_t cbb = (size_t)ntile * 4 * 512 + lane * 8;
        f16x8 Bh[4], Bl[4];
        #pragma unroll
        for (int k = 0; k < 4; ++k) {
            Bh[k] = *(const f16x8*)&Whi[cbb + k * 512];
            Bl[k] = *(const f16x8*)&Wlo[cbb + k * 512];
        }
        f32x4 acc0 = {0.f, 0.f, 0.f, 0.f};
        f32x4 acc1 = {0.f, 0.f, 0.f, 0.f};
        #pragma unroll
        for (int k = 0; k < 4; ++k) {
            acc0 = __builtin_amdgcn_mfma_f32_16x16x32_f16(Ah[k], Bh[k], acc0, 0, 0, 0);
            acc1 = __builtin_amdgcn_mfma_f32_16x16x32_f16(Ah[k], Bl[k], acc1, 0, 0, 0);
            acc1 = __builtin_amdgcn_mfma_f32_16x16x32_f16(Al[k], Bh[k], acc1, 0, 0, 0);
        }
        const int col = ntile * 16 + (lane & 15);
        const float bias = bd[col];
        #pragma unroll
        for (int reg = 0; reg < 4; ++reg) {
            out[(size_t)(m0 + r0 + reg) * NV + col] = acc0[reg] + acc1[reg] + bias;
        }
    }
}

// ---------------- Kernel C (fallback, fp32 vector) ----------------
__global__ __launch_bounds__(256) void k_dense(
    const float* __restrict__ y, const float* __restrict__ Wd,
    const float* __restrict__ bd, float* __restrict__ out)
{
    __shared__ float ys[64 * HD];
    const int r0 = blockIdx.x * 64;
    const int v0 = blockIdx.y * 128;
    const int tid = threadIdx.x;
    for (int idx = tid; idx < 64 * HD; idx += 256) ys[idx] = y[(size_t)r0 * HD + idx];
    __syncthreads();
    const int tx = tid & 31;
    const int ty = tid >> 5;
    const int v = v0 + tx * 4;
    float4 bd4 = *(const float4*)&bd[v];
    float acc[8][4] = {};
    const float* yrow = &ys[(ty * 8) * HD];
    #pragma unroll 4
    for (int e = 0; e < HD; ++e) {
        float4 wv = *(const float4*)&Wd[(size_t)e * NV + v];
        #pragma unroll
        for (int j = 0; j < 8; ++j) {
            float yv = yrow[j * HD + e];
            acc[j][0] = fmaf(yv, wv.x, acc[j][0]);
            acc[j][1] = fmaf(yv, wv.y, acc[j][1]);
            acc[j][2] = fmaf(yv, wv.z, acc[j][2]);
            acc[j][3] = fmaf(yv, wv.w, acc[j][3]);
        }
    }
    #pragma unroll
    for (int j = 0; j < 8; ++j) {
        int rr = r0 + ty * 8 + j;
        float4 o4;
        o4.x = acc[j][0] + bd4.x;
        o4.y = acc[j][1] + bd4.y;
        o4.z = acc[j][2] + bd4.z;
        o4.w = acc[j][3] + bd4.w;
        *(float4*)&out[(size_t)rr * NV + v] = o4;
    }
}

extern "C" void kernel_launch(void* const* d_in, const int* in_sizes, int n_in,
                              void* d_out, int out_size, void* d_ws, size_t ws_size,
                              hipStream_t stream)
{
    const int*   inputs = (const int*)  d_in[0];
    const float* emb    = (const float*)d_in[1];
    const float* W0     = (const float*)d_in[2];
    const float* U0     = (const float*)d_in[3];
    const float* b0     = (const float*)d_in[4];
    const float* W1     = (const float*)d_in[5];
    const float* U1     = (const float*)d_in[6];
    const float* b1     = (const float*)d_in[7];
    const float* Wd     = (const float*)d_in[8];
    const float* bd     = (const float*)d_in[9];
    float* out = (float*)d_out;

    // ws layout (MFMA path): Z0x 8MB | yy 2MB | Whi 8MB | Wlo 8MB | yhi 1MB | ylo 1MB
    const size_t Z0X_B = (size_t)8 * 1024 * 1024;
    const size_t YY_B  = (size_t)2 * 1024 * 1024;
    const size_t WSP_B = (size_t)8000 * 512 * 2;        // 8,192,000
    const size_t YSP_B = (size_t)1024 * 512 * 2;        // 1,048,576
    const size_t NEED  = Z0X_B + YY_B + 2 * WSP_B + 2 * YSP_B + 4096;

    char* ws = (char*)d_ws;

    if (ws_size >= NEED) {
        float*     Z0x = (float*)ws;
        float*     yy  = (float*)(ws + Z0X_B);
        _Float16*  Whi = (_Float16*)(ws + Z0X_B + YY_B);
        _Float16*  Wlo = (_Float16*)(ws + Z0X_B + YY_B + WSP_B);
        _Float16*  yhi = (_Float16*)(ws + Z0X_B + YY_B + 2 * WSP_B);
        _Float16*  ylo = (_Float16*)(ws + Z0X_B + YY_B + 2 * WSP_B + YSP_B);

        k_prep<<<2512, 256, 0, stream>>>(inputs, emb, W0, b0, Z0x, Wd, Whi, Wlo);
        k_lstm_m2<<<4, 256, 0, stream>>>(Z0x, U0, W1, U1, b1, yy);
        k_ysplit<<<256, 256, 0, stream>>>(yy, yhi, ylo);
        k_dense_mfma<<<dim3(64, 100), 256, 0, stream>>>(yhi, ylo, Whi, Wlo, bd, out);
    } else {
        // small-ws fallback: Z0x in d_out tail, yy in ws, fp32 dense
        float* yy = (float*)ws;
        size_t out_bytes = (size_t)out_size * sizeof(float);
        float* Z0x = (float*)((char*)d_out + out_bytes - Z0X_B);

        k_prep<<<2512, 256, 0, stream>>>(inputs, emb, W0, b0, Z0x,
                                         Wd, nullptr, nullptr);
        k_lstm_m2<<<4, 256, 0, stream>>>(Z0x, U0, W1, U1, b1, yy);
        k_dense<<<dim3(64, 250), 256, 0, stream>>>(yy, Wd, bd, out);
    }
}